// Round 1
// baseline (870.479 us; speedup 1.0000x reference)
//
#include <hip/hip_runtime.h>

// LSTM autoencoder: 4 stacked LSTM layers, all 64->64, B=512, T=256.
// One workgroup per batch element; thread = gate row (256 gates = 4*H).
// Weights live in VGPRs as packed f16x2; x_t / h broadcast via v_readlane
// (SGPR operand into v_dot2_f32_f16). State (c,h) and activations in fp32.

typedef _Float16 h2_t __attribute__((ext_vector_type(2)));

#define T_SEQ 256
#define HID   64
#define NGATE 256   // 4*HID

#if __has_builtin(__builtin_amdgcn_fdot2)
#define USE_DOT2 1
#else
#define USE_DOT2 0
#endif

__device__ __forceinline__ float fast_rcp(float x) {
#if __has_builtin(__builtin_amdgcn_rcpf)
    return __builtin_amdgcn_rcpf(x);
#else
    return 1.0f / x;
#endif
}

__device__ __forceinline__ float sigm(float x) {
    return fast_rcp(1.0f + __expf(-x));
}
__device__ __forceinline__ float tanh_fast(float x) {
    return 2.0f * fast_rcp(1.0f + __expf(-2.0f * x)) - 1.0f;
}

// dot2 accumulate: a.x*b.x + a.y*b.y + c  (f32 accumulate)
__device__ __forceinline__ float dot2acc(h2_t a, h2_t b, float c) {
#if USE_DOT2
    return __builtin_amdgcn_fdot2(a, b, c, false);
#else
    return c + (float)a.x * (float)b.x + (float)a.y * (float)b.y;
#endif
}

// broadcast lane k's packed pair to all lanes (lands in an SGPR)
__device__ __forceinline__ h2_t bc(int v, int k) {
    return __builtin_bit_cast(h2_t, __builtin_amdgcn_readlane(v, k));
}

__global__ __launch_bounds__(256)
void lstm_layer(const float* __restrict__ x,   // [B, T, 64]
                float* __restrict__ out,       // [B, T, 64]
                const float* __restrict__ Wih, // [256, 64]
                const float* __restrict__ Whh, // [256, 64]
                const float* __restrict__ bih, // [256]
                const float* __restrict__ bhh) // [256]
{
    __shared__ h2_t  x2s[T_SEQ * 32];  // 32 KB: whole input sequence, packed f16
    __shared__ h2_t  h2s[32];          // hidden state, packed f16
    __shared__ float acts[NGATE];      // gate activations (fp32)

    const int tid  = threadIdx.x;      // gate index g in [0,256)
    const int b    = blockIdx.x;       // batch element
    const int lane = tid & 63;

    // ---- weight rows for this gate into registers, packed f16x2 ----
    h2_t wih2[32], whh2[32];
    {
        const float2* wi = (const float2*)(Wih + tid * HID);
        const float2* wh = (const float2*)(Whh + tid * HID);
#pragma unroll
        for (int k = 0; k < 32; ++k) {
            float2 a = wi[k];
            float2 c = wh[k];
            h2_t p; p.x = (_Float16)a.x; p.y = (_Float16)a.y; wih2[k] = p;
            h2_t q; q.x = (_Float16)c.x; q.y = (_Float16)c.y; whh2[k] = q;
        }
    }
    const float bsum = bih[tid] + bhh[tid];

    // ---- stage this batch element's x sequence into LDS (f16-packed) ----
    {
        const float4* src = (const float4*)(x + (size_t)b * T_SEQ * HID);
#pragma unroll
        for (int j = 0; j < 16; ++j) {
            float4 v = src[tid + j * 256];
            int h2i = (tid + j * 256) * 2;
            h2_t p0; p0.x = (_Float16)v.x; p0.y = (_Float16)v.y;
            h2_t p1; p1.x = (_Float16)v.z; p1.y = (_Float16)v.w;
            x2s[h2i]     = p0;
            x2s[h2i + 1] = p1;
        }
    }
    if (tid < 32) {
        h2_t z; z.x = (_Float16)0.0f; z.y = (_Float16)0.0f;
        h2s[tid] = z;
    }
    float c_state = 0.0f;  // valid in tid<64

    float* ob = out + (size_t)b * T_SEQ * HID;

    __syncthreads();

    const bool  is_g  = ((tid >> 6) == 2);     // wave-uniform gate role
    const float scale = is_g ? 2.0f : 1.0f;    // tanh(x) = 2*sigm(2x)-1

    for (int t = 0; t < T_SEQ; ++t) {
        // lane-distributed operands for this step
        int x2r = __builtin_bit_cast(int, x2s[t * 32 + (lane & 31)]);
        int h2r = __builtin_bit_cast(int, h2s[lane & 31]);

        float a0 = bsum, a1 = 0.0f, a2 = 0.0f, a3 = 0.0f;
#pragma unroll
        for (int k = 0; k < 32; k += 4) {
            a0 = dot2acc(wih2[k + 0], bc(x2r, k + 0), a0);
            a1 = dot2acc(wih2[k + 1], bc(x2r, k + 1), a1);
            a2 = dot2acc(wih2[k + 2], bc(x2r, k + 2), a2);
            a3 = dot2acc(wih2[k + 3], bc(x2r, k + 3), a3);
        }
#pragma unroll
        for (int k = 0; k < 32; k += 4) {
            a0 = dot2acc(whh2[k + 0], bc(h2r, k + 0), a0);
            a1 = dot2acc(whh2[k + 1], bc(h2r, k + 1), a1);
            a2 = dot2acc(whh2[k + 2], bc(h2r, k + 2), a2);
            a3 = dot2acc(whh2[k + 3], bc(h2r, k + 3), a3);
        }
        float pre = (a0 + a1) + (a2 + a3);

        // i,f,o: sigmoid; g: tanh = 2*sigm(2x)-1  (single exp path, wave-uniform)
        float s = sigm(scale * pre);
        float a = is_g ? (2.0f * s - 1.0f) : s;
        acts[tid] = a;
        __syncthreads();

        if (tid < 64) {  // wave 0 does the state update
            float gi = acts[tid];
            float gf = acts[64 + tid];
            float gg = acts[128 + tid];
            float go = acts[192 + tid];
            c_state = gf * c_state + gi * gg;
            float h = go * tanh_fast(c_state);
            ob[t * HID + tid] = h;                       // fp32 layer output
            ((_Float16*)h2s)[tid] = (_Float16)h;         // f16 for next matvec
        }
        __syncthreads();
    }
}

// Fallback scratch in case ws_size is too small (33.6 MB needed)
__device__ float g_scratch[512 * 256 * 64];

extern "C" void kernel_launch(void* const* d_in, const int* in_sizes, int n_in,
                              void* d_out, int out_size, void* d_ws, size_t ws_size,
                              hipStream_t stream) {
    const float* x = (const float*)d_in[0];
    float* out = (float*)d_out;

    const size_t buf_elems = (size_t)512 * 256 * 64;
    float* buf;
    if (ws_size >= buf_elems * sizeof(float)) {
        buf = (float*)d_ws;
    } else {
        void* p = nullptr;
        hipGetSymbolAddress(&p, HIP_SYMBOL(g_scratch));
        buf = (float*)p;
    }

    auto launch = [&](const float* xi, float* ho, int wb) {
        lstm_layer<<<512, 256, 0, stream>>>(
            xi, ho,
            (const float*)d_in[wb + 0],   // Wih
            (const float*)d_in[wb + 1],   // Whh
            (const float*)d_in[wb + 2],   // bih
            (const float*)d_in[wb + 3]);  // bhh
    };

    launch(x,   buf, 1);    // enc0: x   -> buf
    launch(buf, out, 5);    // enc1: buf -> out
    launch(out, buf, 9);    // dec0: out -> buf
    launch(buf, out, 13);   // dec1: buf -> out (final)
}

// Round 2
// 591.822 us; speedup vs baseline: 1.4708x; 1.4708x over previous
//
#include <hip/hip_runtime.h>

// LSTM autoencoder: 4 layers 64->64, B=512, T=256.
// Producer/consumer wave pair per batch element (block=128):
//   wave0 (producer): xg[t,g] = W_ih . x_t + b  -- no recurrence dep, runs
//     one CHUNK ahead, double-buffered in LDS, x prefetched in registers.
//   wave1 (consumer): recurrence  g = xg + W_hh . h ; activations; c,h update.
// Each lane owns hidden unit `lane` and its 4 gate rows (rows g*64+lane),
// weights packed f16x2 in VGPRs (4x32 = 128 VGPRs). Broadcast of x_t / h
// pairs via v_readlane feeding v_dot2_f32_f16 (f32 accumulate).
// h repack for next step via 2x ds_bpermute (no LDS write->read round trip).

typedef _Float16 h2_t __attribute__((ext_vector_type(2)));

#define T_SEQ  256
#define HID    64
#define CHUNK  8
#define NCHUNK (T_SEQ / CHUNK)   // 32

__device__ __forceinline__ float fast_rcp(float x) { return __builtin_amdgcn_rcpf(x); }
__device__ __forceinline__ float sigm(float x) { return fast_rcp(1.0f + __expf(-x)); }
__device__ __forceinline__ float tanh_fast(float x) {
    return 2.0f * fast_rcp(1.0f + __expf(-2.0f * x)) - 1.0f;
}
__device__ __forceinline__ float dot2acc(h2_t a, h2_t b, float c) {
    return __builtin_amdgcn_fdot2(a, b, c, false);
}
// broadcast lane k's packed f16 pair to all lanes (SGPR operand into dot2)
__device__ __forceinline__ h2_t bc(int v, int k) {
    return __builtin_bit_cast(h2_t, __builtin_amdgcn_readlane(v, k));
}

__global__ __launch_bounds__(128)
void lstm_layer_pc(const float* __restrict__ x,    // [B, T, 64]
                   float* __restrict__ out,        // [B, T, 64]
                   const float* __restrict__ Wih,  // [256, 64]
                   const float* __restrict__ Whh,  // [256, 64]
                   const float* __restrict__ bih,  // [256]
                   const float* __restrict__ bhh)  // [256]
{
    __shared__ float4 xg[2][CHUNK][HID];   // 16 KB double-buffered xg chunks

    const int  tid  = threadIdx.x;
    const int  lane = tid & 63;
    const bool isC  = (tid >= 64);         // wave1 = consumer
    const int  b    = blockIdx.x;

    // ---- role weight matrix (rows g*64+lane), packed f16x2 in VGPRs ----
    h2_t w[4][32];
    {
        const float* Wm = isC ? Whh : Wih;
#pragma unroll
        for (int g = 0; g < 4; ++g) {
            const float2* wr = (const float2*)(Wm + (g * 64 + lane) * HID);
#pragma unroll
            for (int k = 0; k < 32; ++k) {
                float2 v = wr[k];
                h2_t p; p.x = (_Float16)v.x; p.y = (_Float16)v.y;
                w[g][k] = p;
            }
        }
    }

    // ---- producer-only state: biases + x prefetch registers ----
    float bs0 = 0.f, bs1 = 0.f, bs2 = 0.f, bs3 = 0.f;
    const float2* xp = (const float2*)(x + (size_t)b * T_SEQ * HID) + (lane & 31);
    float2 nx[CHUNK];
    if (!isC) {
        bs0 = bih[lane]       + bhh[lane];
        bs1 = bih[64 + lane]  + bhh[64 + lane];
        bs2 = bih[128 + lane] + bhh[128 + lane];
        bs3 = bih[192 + lane] + bhh[192 + lane];
#pragma unroll
        for (int s = 0; s < CHUNK; ++s) nx[s] = xp[s * 32];   // chunk 0
    }

    // ---- consumer-only state ----
    float c_state = 0.0f;
    int   h2r     = 0;                       // packed (h[2k],h[2k+1]) in lane k; h0 = 0
    const int a0i = (lane & 31) << 3;        // bpermute byte addr of lane 2*(lane&31)
    float* ob = out + (size_t)b * T_SEQ * HID + lane;

    // iteration c: producer fills chunk c+1, consumer drains chunk c
    for (int c = -1; c < NCHUNK; ++c) {
        if (!isC) {
            const int k = c + 1;
            if (k < NCHUNK) {
                float2 cx[CHUNK];
#pragma unroll
                for (int s = 0; s < CHUNK; ++s) cx[s] = nx[s];
                if (k + 1 < NCHUNK) {        // prefetch next chunk's x
#pragma unroll
                    for (int s = 0; s < CHUNK; ++s)
                        nx[s] = xp[((k + 1) * CHUNK + s) * 32];
                }
#pragma unroll
                for (int s = 0; s < CHUNK; ++s) {
                    h2_t xv; xv.x = (_Float16)cx[s].x; xv.y = (_Float16)cx[s].y;
                    int x2r = __builtin_bit_cast(int, xv);
                    float A0 = bs0, A1 = bs1, A2 = bs2, A3 = bs3;
                    float B0 = 0.f, B1 = 0.f, B2 = 0.f, B3 = 0.f;
#pragma unroll
                    for (int kk = 0; kk < 16; ++kk) {
                        h2_t sv = bc(x2r, kk);
                        A0 = dot2acc(w[0][kk], sv, A0);
                        A1 = dot2acc(w[1][kk], sv, A1);
                        A2 = dot2acc(w[2][kk], sv, A2);
                        A3 = dot2acc(w[3][kk], sv, A3);
                    }
#pragma unroll
                    for (int kk = 16; kk < 32; ++kk) {
                        h2_t sv = bc(x2r, kk);
                        B0 = dot2acc(w[0][kk], sv, B0);
                        B1 = dot2acc(w[1][kk], sv, B1);
                        B2 = dot2acc(w[2][kk], sv, B2);
                        B3 = dot2acc(w[3][kk], sv, B3);
                    }
                    float4 r;
                    r.x = A0 + B0; r.y = A1 + B1; r.z = A2 + B2; r.w = A3 + B3;
                    xg[k & 1][s][lane] = r;
                }
            }
        } else if (c >= 0) {
#pragma unroll 1
            for (int s = 0; s < CHUNK; ++s) {
                float4 xr = xg[c & 1][s][lane];   // bias already folded in
                float A0 = 0.f, A1 = 0.f, A2 = 0.f, A3 = 0.f;
                float B0 = 0.f, B1 = 0.f, B2 = 0.f, B3 = 0.f;
#pragma unroll
                for (int kk = 0; kk < 16; ++kk) {
                    h2_t sv = bc(h2r, kk);
                    A0 = dot2acc(w[0][kk], sv, A0);
                    A1 = dot2acc(w[1][kk], sv, A1);
                    A2 = dot2acc(w[2][kk], sv, A2);
                    A3 = dot2acc(w[3][kk], sv, A3);
                }
#pragma unroll
                for (int kk = 16; kk < 32; ++kk) {
                    h2_t sv = bc(h2r, kk);
                    B0 = dot2acc(w[0][kk], sv, B0);
                    B1 = dot2acc(w[1][kk], sv, B1);
                    B2 = dot2acc(w[2][kk], sv, B2);
                    B3 = dot2acc(w[3][kk], sv, B3);
                }
                float pi = A0 + B0 + xr.x;
                float pf = A1 + B1 + xr.y;
                float pg = A2 + B2 + xr.z;
                float po = A3 + B3 + xr.w;

                float gi = sigm(pi);
                float gf = sigm(pf);
                float gg = tanh_fast(pg);
                float go = sigm(po);
                c_state = gf * c_state + gi * gg;
                float h = go * tanh_fast(c_state);

                ob[(c * CHUNK + s) * HID] = h;

                // repack h -> (h[2k],h[2k+1]) f16 pair in lane k via bpermute
                _Float16 hf = (_Float16)h;
                int hv = (int)__builtin_bit_cast(unsigned short, hf);  // zero-ext
                int p0 = __builtin_amdgcn_ds_bpermute(a0i, hv);
                int p1 = __builtin_amdgcn_ds_bpermute(a0i + 4, hv);
                h2r = p0 | (p1 << 16);
            }
        }
        __syncthreads();
    }
}

// Fallback scratch in case ws_size is too small (33.6 MB needed)
__device__ float g_scratch[512 * 256 * 64];

extern "C" void kernel_launch(void* const* d_in, const int* in_sizes, int n_in,
                              void* d_out, int out_size, void* d_ws, size_t ws_size,
                              hipStream_t stream) {
    const float* x = (const float*)d_in[0];
    float* out = (float*)d_out;

    const size_t buf_elems = (size_t)512 * 256 * 64;
    float* buf;
    if (ws_size >= buf_elems * sizeof(float)) {
        buf = (float*)d_ws;
    } else {
        void* p = nullptr;
        hipGetSymbolAddress(&p, HIP_SYMBOL(g_scratch));
        buf = (float*)p;
    }

    auto launch = [&](const float* xi, float* ho, int wb) {
        lstm_layer_pc<<<512, 128, 0, stream>>>(
            xi, ho,
            (const float*)d_in[wb + 0],   // Wih
            (const float*)d_in[wb + 1],   // Whh
            (const float*)d_in[wb + 2],   // bih
            (const float*)d_in[wb + 3]);  // bhh
    };

    launch(x,   buf, 1);    // enc0
    launch(buf, out, 5);    // enc1
    launch(out, buf, 9);    // dec0
    launch(buf, out, 13);   // dec1 (final)
}